// Round 1
// baseline (211.488 us; speedup 1.0000x reference)
//
#include <hip/hip_runtime.h>

#define UMAXC   1.0f
#define LAMC    10000.0f
#define INV_LAM 1e-4f
#define EPSC    1e-12f
#define TOLC    1e-6f

// sign(phi(t)) without sqrt: phi = L - R*sqrt(q), q >= EPS > 0
__device__ __forceinline__ bool phi_pos(float t, float A, float p, float N, float b) {
    float q = fmaf(t, fmaf(t, A, -2.0f * p), N);
    q = fmaxf(q, EPSC);
    float L = fmaf(-t, A, p);        // (p - t*A) * U_MAX
    float R = fmaf(t, INV_LAM, b);   // b + t/LAM
    float L2 = L * L;
    float Rq = (R * R) * q;
    if (R < 0.0f) return (L >= 0.0f) || (L2 < Rq);
    return (L > 0.0f) && (L2 > Rq);
}

__device__ __forceinline__ void solve_row(float ux, float uy,
                                          float px, float py,
                                          float vx, float vy,
                                          float& ox, float& oy) {
    float h  = fmaf(px, px, py * py) - 1.0f;            // |p|^2 - SAFE_DIST^2
    float ax = -2.0f * px, ay = -2.0f * py;
    float b  = fmaf(2.0f, h, -2.0f * fmaf(px, vx, py * vy));
    float A  = fmaf(ax, ax, ay * ay);
    float p  = fmaf(ax, ux, ay * uy);
    float N  = fmaf(ux, ux, uy * uy);
    float n  = sqrtf(fmaxf(N, EPSC));
    float s1 = fminf(1.0f, 1.0f / n);
    float u1x = ux * s1, u1y = uy * s1;
    bool feas1 = fmaf(ax, u1x, ay * u1y) <= b + TOLC;

    float t2 = LAMC * (p - b) / fmaf(LAMC, A, 1.0f);
    float u2x = fmaf(-t2, ax, ux), u2y = fmaf(-t2, ay, uy);
    bool ok2 = (t2 >= -TOLC) && (fmaf(u2x, u2x, u2y * u2y) <= 1.0f + TOLC);

    if (feas1) { ox = u1x; oy = u1y; return; }
    if (ok2)   { ox = u2x; oy = u2y; return; }

    // --- branch 3: doubling (early-exit == reference's frozen where) ---
    float th = 1.0f;
    #pragma unroll 1
    for (int k = 0; k < 40; ++k) {
        if (!phi_pos(th, A, p, N, b)) break;
        th *= 2.0f;
    }
    // --- bisection (24 iters; Newton below recovers full precision) ---
    float lo = 0.0f, hi = th;
    #pragma unroll 1
    for (int k = 0; k < 24; ++k) {
        float mid = 0.5f * (lo + hi);
        bool pos = phi_pos(mid, A, p, N, b);
        lo = pos ? mid : lo;
        hi = pos ? hi : mid;
    }
    float t3 = 0.5f * (lo + hi);
    // --- 3 Newton steps (mirrors reference formulas) ---
    #pragma unroll
    for (int k = 0; k < 3; ++k) {
        float q   = fmaf(t3, fmaf(t3, A, -2.0f * p), N);
        float nrm = sqrtf(fmaxf(q, EPSC));
        float R   = fmaf(t3, INV_LAM, b);
        float f   = fmaf(-t3, A, p) - R * nrm;
        float df  = -A - nrm * INV_LAM - R * fmaf(t3, A, -p) / nrm;
        df = (fabsf(df) > 1e-8f) ? df : -1e-8f;
        t3 = t3 - f / df;
    }
    float q3   = fmaf(t3, fmaf(t3, A, -2.0f * p), N);
    float nrm3 = sqrtf(fmaxf(q3, EPSC));
    float k3   = fmaxf(nrm3, 1.0f);   // U_MAX = 1
    float inv  = 1.0f / k3;
    ox = fmaf(-t3, ax, ux) * inv;
    oy = fmaf(-t3, ay, uy) * inv;
}

__global__ __launch_bounds__(256) void cbf_kernel(const float4* __restrict__ u4,
                                                  const float4* __restrict__ obs4,
                                                  float4* __restrict__ out4,
                                                  int npair) {
    int i = blockIdx.x * blockDim.x + threadIdx.x;
    if (i >= npair) return;
    float4 u  = u4[i];
    float4 o0 = obs4[3 * i + 0];
    float4 o1 = obs4[3 * i + 1];
    float4 o2 = obs4[3 * i + 2];
    // row 2i:   p=(o0.z,o0.w)  v=(o1.x,o1.y)
    // row 2i+1: p=(o2.x,o2.y)  v=(o2.z,o2.w)
    float4 r;
    solve_row(u.x, u.y, o0.z, o0.w, o1.x, o1.y, r.x, r.y);
    solve_row(u.z, u.w, o2.x, o2.y, o2.z, o2.w, r.z, r.w);
    out4[i] = r;
}

extern "C" void kernel_launch(void* const* d_in, const int* in_sizes, int n_in,
                              void* d_out, int out_size, void* d_ws, size_t ws_size,
                              hipStream_t stream) {
    const float* u_nom = (const float*)d_in[0];
    const float* obs   = (const float*)d_in[1];
    float* out = (float*)d_out;
    int rows  = in_sizes[0] / 2;      // B
    int npair = rows / 2;             // 2 rows per thread
    int blocks = (npair + 255) / 256;
    cbf_kernel<<<blocks, 256, 0, stream>>>((const float4*)u_nom,
                                           (const float4*)obs,
                                           (float4*)out, npair);
}

// Round 2
// 183.297 us; speedup vs baseline: 1.1538x; 1.1538x over previous
//
#include <hip/hip_runtime.h>

#define LAMC    10000.0f
#define INV_LAM 1e-4f
#define EPSC    1e-12f
#define TOLC    1e-6f
#define BLK     256
#define RPB     (2 * BLK)   // rows per block

// sign(phi(t)) without sqrt: phi = L - R*sqrt(q), q >= EPS > 0
__device__ __forceinline__ bool phi_pos(float t, float A, float p, float N, float b) {
    float q  = fmaxf(fmaf(t, fmaf(t, A, -2.0f * p), N), EPSC);
    float L  = fmaf(-t, A, p);        // (p - t*A) * U_MAX
    float R  = fmaf(t, INV_LAM, b);   // b + t/LAM
    float L2 = L * L;
    float Rq = (R * R) * q;
    return (R < 0.0f) ? ((L >= 0.0f) || (L2 < Rq))
                      : ((L >  0.0f) && (L2 > Rq));
}

struct Smem {
    float res_x[RPB];
    float res_y[RPB];
    float ux[RPB], uy[RPB], ax[RPB], ay[RPB], b[RPB];
    int   id[RPB];
    int   cnt;
};

__device__ __forceinline__ void phaseA(bool valid, float ux, float uy,
                                       float px, float py, float vx, float vy,
                                       int r, Smem& sm) {
    if (!valid) return;
    float ax = -2.0f * px, ay = -2.0f * py;
    float h  = fmaf(px, px, py * py) - 1.0f;             // |p|^2 - SAFE_DIST^2
    float b  = fmaf(2.0f, h, -2.0f * fmaf(px, vx, py * vy));
    float A  = fmaf(ax, ax, ay * ay);
    float p  = fmaf(ax, ux, ay * uy);
    float n  = sqrtf(fmaxf(fmaf(ux, ux, uy * uy), EPSC));
    float s1 = fminf(1.0f, 1.0f / n);
    float u1x = ux * s1, u1y = uy * s1;
    if (fmaf(ax, u1x, ay * u1y) <= b + TOLC) {
        sm.res_x[r] = u1x; sm.res_y[r] = u1y; return;
    }
    float t2  = LAMC * (p - b) / fmaf(LAMC, A, 1.0f);
    float u2x = fmaf(-t2, ax, ux), u2y = fmaf(-t2, ay, uy);
    if (t2 >= -TOLC && fmaf(u2x, u2x, u2y * u2y) <= 1.0f + TOLC) {
        sm.res_x[r] = u2x; sm.res_y[r] = u2y; return;
    }
    int j = atomicAdd(&sm.cnt, 1);
    sm.ux[j] = ux; sm.uy[j] = uy;
    sm.ax[j] = ax; sm.ay[j] = ay;
    sm.b[j]  = b;  sm.id[j] = r;
}

__global__ __launch_bounds__(BLK) void cbf_kernel(const float4* __restrict__ u4,
                                                  const float4* __restrict__ obs4,
                                                  float4* __restrict__ out4,
                                                  int npair) {
    __shared__ Smem sm;
    int tid = threadIdx.x;
    if (tid == 0) sm.cnt = 0;
    __syncthreads();

    int i = blockIdx.x * BLK + tid;
    bool valid = i < npair;
    float4 u  = make_float4(0.f, 0.f, 0.f, 0.f);
    float4 o0 = u, o1 = u, o2 = u;
    if (valid) {
        u  = u4[i];
        o0 = obs4[3 * i + 0];
        o1 = obs4[3 * i + 1];
        o2 = obs4[3 * i + 2];
    }
    // row 2i:   p=(o0.z,o0.w)  v=(o1.x,o1.y)
    // row 2i+1: p=(o2.x,o2.y)  v=(o2.z,o2.w)
    phaseA(valid, u.x, u.y, o0.z, o0.w, o1.x, o1.y, 2 * tid,     sm);
    phaseA(valid, u.z, u.w, o2.x, o2.y, o2.z, o2.w, 2 * tid + 1, sm);
    __syncthreads();

    int M = sm.cnt;
    #pragma unroll 1
    for (int j = tid; j < M; j += BLK) {
        float ux = sm.ux[j], uy = sm.uy[j];
        float ax = sm.ax[j], ay = sm.ay[j];
        float b  = sm.b[j];
        float A  = fmaf(ax, ax, ay * ay);
        float p  = fmaf(ax, ux, ay * uy);
        float N  = fmaf(ux, ux, uy * uy);

        // phi(0) sign decides which reference path we replicate.
        bool pos0 = phi_pos(0.0f, A, p, N, b);
        float t3;
        if (pos0) {
            // unique root in (0, th]: th makes L<=0 and R>=0 -> phi<=0
            float th = fmaxf(1.0f, fmaxf(p / fmaxf(A, 1e-30f), -LAMC * b));
            float lo = 0.0f, hi = th;
            #pragma unroll 1
            for (int k = 0; k < 28; ++k) {
                float mid = 0.5f * (lo + hi);
                bool pos = phi_pos(mid, A, p, N, b);
                lo = pos ? mid : lo;
                hi = pos ? hi : mid;
            }
            t3 = 0.5f * (lo + hi);
            #pragma unroll
            for (int k = 0; k < 4; ++k) {
                float q   = fmaxf(fmaf(t3, fmaf(t3, A, -2.0f * p), N), EPSC);
                float nrm = sqrtf(q);
                float R   = fmaf(t3, INV_LAM, b);
                float f   = fmaf(-t3, A, p) - R * nrm;
                float df  = -A - nrm * INV_LAM - R * fmaf(t3, A, -p) / nrm;
                df = (fabsf(df) > 1e-8f) ? df : -1e-8f;
                t3 = fminf(fmaxf(t3 - f / df, lo), hi);  // safeguarded
            }
        } else {
            // reference: bisection collapses to ~0, then 3 FREE Newton steps
            t3 = 0.0f;
            #pragma unroll
            for (int k = 0; k < 3; ++k) {
                float q   = fmaxf(fmaf(t3, fmaf(t3, A, -2.0f * p), N), EPSC);
                float nrm = sqrtf(q);
                float R   = fmaf(t3, INV_LAM, b);
                float f   = fmaf(-t3, A, p) - R * nrm;
                float df  = -A - nrm * INV_LAM - R * fmaf(t3, A, -p) / nrm;
                df = (fabsf(df) > 1e-8f) ? df : -1e-8f;
                t3 = t3 - f / df;
            }
        }
        float q3  = fmaxf(fmaf(t3, fmaf(t3, A, -2.0f * p), N), EPSC);
        float k3  = fmaxf(sqrtf(q3), 1.0f);   // U_MAX = 1
        float inv = 1.0f / k3;
        int r = sm.id[j];
        sm.res_x[r] = fmaf(-t3, ax, ux) * inv;
        sm.res_y[r] = fmaf(-t3, ay, uy) * inv;
    }
    __syncthreads();

    if (valid) {
        float4 r;
        r.x = sm.res_x[2 * tid];     r.y = sm.res_y[2 * tid];
        r.z = sm.res_x[2 * tid + 1]; r.w = sm.res_y[2 * tid + 1];
        out4[i] = r;
    }
}

extern "C" void kernel_launch(void* const* d_in, const int* in_sizes, int n_in,
                              void* d_out, int out_size, void* d_ws, size_t ws_size,
                              hipStream_t stream) {
    const float* u_nom = (const float*)d_in[0];
    const float* obs   = (const float*)d_in[1];
    float* out = (float*)d_out;
    int rows   = in_sizes[0] / 2;     // B
    int npair  = rows / 2;            // 2 rows per thread
    int blocks = (npair + BLK - 1) / BLK;
    cbf_kernel<<<blocks, BLK, 0, stream>>>((const float4*)u_nom,
                                           (const float4*)obs,
                                           (float4*)out, npair);
}